// Round 1
// baseline (113.128 us; speedup 1.0000x reference)
//
#include <hip/hip_runtime.h>
#include <math.h>

// Problem constants (fixed by setup_inputs)
#define NL 4        // n_latents
#define MM 1024     // codebook entries per latent
#define DD 16       // dim per latent
#define PP 16384    // points = N*H*W = 16*32*32
#define PLANE 1024  // H*W
#define NSTRIDE 65536 // z_dim*H*W = 64*1024 (stride between batch images in z)
#define PC 128      // points per chunk (per block)
#define NCHUNK (PP / PC) // 128
#define ZSTR 20     // LDS row stride in floats (16 data + 4 pad; 80B, 16B-aligned)

#if __has_builtin(__builtin_amdgcn_exp2f)
#define EXP2(x) __builtin_amdgcn_exp2f(x)
#else
#define EXP2(x) __expf((x) * 0.6931471805599453f)
#endif

// Kernel 1: for each (l, chunk) accumulate S[l][m] += sum_{p in chunk} exp(alpha*d2(l,p,m))
// Work folded so inner loop is: c = azq + ea[r]; 16 FMA; exp2(c).
//   ef = e * (-2*alpha/ln2),  ea = alpha*|e|^2/ln2,  azq = alpha*|z|^2/ln2
__global__ __launch_bounds__(256, 2)
void latent_dist_kernel(const float* __restrict__ z, const float* __restrict__ e,
                        const float* __restrict__ log_sigma, float* __restrict__ S)
{
    const int t  = threadIdx.x;
    const int pc = blockIdx.x & (NCHUNK - 1);
    const int l  = blockIdx.x >> 7; // / NCHUNK

    const float ls = log_sigma[0];
    const float alpha = -0.5f * __expf(-2.0f * ls);
    const float a2 = alpha * 1.44269504088896340736f; // alpha / ln(2)

    __shared__ __attribute__((aligned(16))) float zs[PC * ZSTR];
    __shared__ float zsq[PC];

    const int p0 = pc * PC;
    const int n  = p0 >> 10;           // p0 / PLANE
    const int q0 = p0 & (PLANE - 1);   // p0 % PLANE
    const float* zb = z + (size_t)n * NSTRIDE + (size_t)(l * DD) * PLANE + q0;

    // Stage 128 points x 16 dims. Global reads coalesced per d-plane; LDS layout
    // transposed to point-major (stride ZSTR) for b128 broadcast reads later.
#pragma unroll
    for (int k = 0; k < (PC * DD) / 256; ++k) {
        int i = k * 256 + t;
        int d = i >> 7;        // i / PC
        int j = i & (PC - 1);  // i % PC
        zs[j * ZSTR + d] = zb[d * PLANE + j];
    }
    __syncthreads();
    if (t < PC) {
        float s = 0.f;
#pragma unroll
        for (int d = 0; d < DD; ++d) { float v = zs[t * ZSTR + d]; s += v * v; }
        zsq[t] = s * a2; // alpha/ln2 folded in
    }
    __syncthreads();

    // Register-cache 4 codebook vectors per thread: m = 4*t + r
    float ef[4][16];
    float ea[4];
    {
        const float* eb = e + ((size_t)l * MM + (size_t)(t * 4)) * DD;
#pragma unroll
        for (int r = 0; r < 4; ++r) {
            float s = 0.f;
#pragma unroll
            for (int d = 0; d < DD; ++d) {
                float v = eb[r * DD + d];
                s += v * v;
                ef[r][d] = v * (-2.0f * a2);
            }
            ea[r] = s * a2;
        }
    }

    float acc[4] = {0.f, 0.f, 0.f, 0.f};
    for (int j = 0; j < PC; ++j) {
        const float4* zj = (const float4*)(zs + j * ZSTR);
        float4 z0 = zj[0], z1 = zj[1], z2 = zj[2], z3 = zj[3];
        float zp[16] = { z0.x, z0.y, z0.z, z0.w,  z1.x, z1.y, z1.z, z1.w,
                         z2.x, z2.y, z2.z, z2.w,  z3.x, z3.y, z3.z, z3.w };
        float azq = zsq[j];
#pragma unroll
        for (int r = 0; r < 4; ++r) {
            float c = azq + ea[r];
#pragma unroll
            for (int d = 0; d < DD; ++d) c = fmaf(ef[r][d], zp[d], c);
            acc[r] += EXP2(c);
        }
    }

    float* Sl = S + l * MM + t * 4;
#pragma unroll
    for (int r = 0; r < 4; ++r) atomicAdd(&Sl[r], acc[r]);
}

// Kernel 2: out = -(1/(L*M)) * sum log(S) + 0.5*z_dim*(2*ls - 1) + log(N*H*W)
__global__ void latent_reduce_kernel(const float* __restrict__ S,
                                     const float* __restrict__ log_sigma,
                                     float* __restrict__ out)
{
    const int t = threadIdx.x;
    float s = 0.f;
    for (int i = t; i < NL * MM; i += 256) s += __logf(S[i]);
#pragma unroll
    for (int off = 32; off > 0; off >>= 1) s += __shfl_down(s, off, 64);
    __shared__ float red[4];
    if ((t & 63) == 0) red[t >> 6] = s;
    __syncthreads();
    if (t == 0) {
        float tot = red[0] + red[1] + red[2] + red[3];
        float ls = log_sigma[0];
        float res = -tot / (float)(NL * MM)
                  + 0.5f * 64.0f * (2.0f * ls - 1.0f)
                  + 9.70406052783923f; // ln(16384)
        out[0] = res;
    }
}

extern "C" void kernel_launch(void* const* d_in, const int* in_sizes, int n_in,
                              void* d_out, int out_size, void* d_ws, size_t ws_size,
                              hipStream_t stream)
{
    const float* z  = (const float*)d_in[0];
    const float* e  = (const float*)d_in[1];
    const float* ls = (const float*)d_in[2];
    float* S   = (float*)d_ws;
    float* out = (float*)d_out;

    // ws is re-poisoned before every launch; zero the accumulator region.
    hipMemsetAsync(S, 0, NL * MM * sizeof(float), stream);
    latent_dist_kernel<<<NL * NCHUNK, 256, 0, stream>>>(z, e, ls, S);
    latent_reduce_kernel<<<1, 256, 0, stream>>>(S, ls, out);
}

// Round 2
// 102.865 us; speedup vs baseline: 1.0998x; 1.0998x over previous
//
#include <hip/hip_runtime.h>
#include <math.h>

// Problem constants (fixed by setup_inputs)
#define NL 4          // n_latents
#define MM 1024       // codebook entries per latent
#define DD 16         // dim per latent
#define PP 16384      // points = N*H*W
#define PLANE 1024    // H*W
#define NSTRIDE 65536 // z_dim*H*W
#define CHUNK 512     // points per workgroup (half a plane)
#define NCHUNK (PP / CHUNK)   // 32
#define MGROUP 128    // codes per workgroup (4 waves x 32)
#define NMG (MM / MGROUP)     // 8
#define ZSTR 20       // LDS stride per point in f16 units (16 data + 4 pad = 40B)

#if __has_builtin(__builtin_amdgcn_exp2f)
#define EXP2(x) __builtin_amdgcn_exp2f(x)
#else
#define EXP2(x) exp2f(x)
#endif

typedef _Float16 half4v  __attribute__((ext_vector_type(4)));
typedef _Float16 half8v  __attribute__((ext_vector_type(8)));
typedef float    float16v __attribute__((ext_vector_type(16)));

// Per (l, m-strip of 32 codes, p-chunk of 512 points):
//   cross = e_tile(32xK16) . z_tile(K16x32) via v_mfma_f32_32x32x16_f16
//   exponent(log2) = a2*zsq[p] + a2*esq[m] - 2*a2*cross   (a2 = alpha/ln2)
//   acc[m] += 2^exponent, reduced over the 32-point cols, stored as chunk-partial.
// MFMA 32x32 C/D layout (HW-verified): col=lane&31, row=(reg&3)+8*(reg>>2)+4*(lane>>5)
// A layout (analog of verified 16x16x32): A[row=lane&31][k=(lane>>5)*8+j], B same on cols.
template <bool PART>
__global__ __launch_bounds__(256, 4)
void latent_dist_kernel(const float* __restrict__ z, const float* __restrict__ e,
                        const float* __restrict__ log_sigma, float* __restrict__ Spart)
{
    const int t    = threadIdx.x;
    const int lane = t & 63;
    const int wave = t >> 6;
    const int ln31 = lane & 31;
    const int hf   = lane >> 5;

    const int bid = blockIdx.x;
    const int c   = bid & (NCHUNK - 1);       // p-chunk
    const int mg  = (bid >> 5) & (NMG - 1);   // m-group
    const int l   = bid >> 8;                 // latent

    const float ls   = log_sigma[0];
    const float alpha = -0.5f * __expf(-2.0f * ls);
    const float a2   = alpha * 1.44269504088896340736f; // alpha/ln2
    const float m2a2 = -2.0f * a2;

    __shared__ __attribute__((aligned(16))) _Float16 zh[CHUNK * ZSTR];
    __shared__ float azqs[CHUNK];
    __shared__ float esqs[MGROUP];

    // ---- Stage z chunk: global f32 (coalesced) -> LDS f16 point-major; exact f32 zsq.
    const int n  = c >> 1;
    const int q0 = (c & 1) * CHUNK;
    const float* zb = z + (size_t)n * NSTRIDE + (size_t)l * DD * PLANE + q0;

    float sq[2] = {0.f, 0.f};
#pragma unroll
    for (int dp = 0; dp < 8; ++dp) {
#pragma unroll
        for (int j = 0; j < 2; ++j) {
            const int pl = j * 256 + t;
            float v0 = zb[(2 * dp)     * PLANE + pl];
            float v1 = zb[(2 * dp + 1) * PLANE + pl];
            sq[j] += v0 * v0 + v1 * v1;
            union { _Float16 h[2]; unsigned u; } pk;
            pk.h[0] = (_Float16)v0; pk.h[1] = (_Float16)v1;
            *(unsigned*)(&zh[pl * ZSTR + 2 * dp]) = pk.u; // 4B-aligned packed store
        }
    }
    azqs[t]       = sq[0] * a2;
    azqs[256 + t] = sq[1] * a2;

    // ---- A fragment (codes) + esq, exact in f32.
    const int m0 = mg * MGROUP + wave * 32;
    const float* eb = e + ((size_t)l * MM + m0 + ln31) * DD + hf * 8;
    float4 a0 = *(const float4*)eb;
    float4 a1 = *(const float4*)(eb + 4);
    float esq_p = a0.x*a0.x + a0.y*a0.y + a0.z*a0.z + a0.w*a0.w
                + a1.x*a1.x + a1.y*a1.y + a1.z*a1.z + a1.w*a1.w;
    esq_p += __shfl_xor(esq_p, 32, 64);           // combine the two k-halves
    esqs[wave * 32 + ln31] = esq_p;               // both halves write same value

    half8v Af;
    Af[0] = (_Float16)a0.x; Af[1] = (_Float16)a0.y;
    Af[2] = (_Float16)a0.z; Af[3] = (_Float16)a0.w;
    Af[4] = (_Float16)a1.x; Af[5] = (_Float16)a1.y;
    Af[6] = (_Float16)a1.z; Af[7] = (_Float16)a1.w;

    __syncthreads();

    // Per-reg bias = a2*esq[row(r)], constant over the p-loop.
    float bias[16];
#pragma unroll
    for (int r = 0; r < 16; ++r) {
        const int row = (r & 3) + 8 * (r >> 2) + 4 * hf;
        bias[r] = esqs[wave * 32 + row] * a2;
    }

    float16v acc, zeroC;
#pragma unroll
    for (int r = 0; r < 16; ++r) { acc[r] = 0.f; zeroC[r] = 0.f; }

    const _Float16* zrow = zh + ln31 * ZSTR + hf * 8;
#pragma unroll 4
    for (int pt = 0; pt < CHUNK / 32; ++pt) {
        const float az = azqs[pt * 32 + ln31];           // ds_read_b32 (broadcast)
        const _Float16* bp = zrow + pt * 32 * ZSTR;
        half4v b0 = *(const half4v*)bp;                  // ds_read_b64 x2, 2-way bank alias = free
        half4v b1 = *(const half4v*)(bp + 4);
        half8v Bf = __builtin_shufflevector(b0, b1, 0, 1, 2, 3, 4, 5, 6, 7);
        float16v dd = __builtin_amdgcn_mfma_f32_32x32x16_f16(Af, Bf, zeroC, 0, 0, 0);
#pragma unroll
        for (int r = 0; r < 16; ++r) {
            float cc = fmaf(m2a2, dd[r], az + bias[r]);
            acc[r] += EXP2(cc);
        }
    }

    // Reduce over the 32 cols (points) inside each half-wave.
#pragma unroll
    for (int r = 0; r < 16; ++r) {
        float v = acc[r];
        v += __shfl_xor(v, 16, 64);
        v += __shfl_xor(v, 8, 64);
        v += __shfl_xor(v, 4, 64);
        v += __shfl_xor(v, 2, 64);
        v += __shfl_xor(v, 1, 64);
        acc[r] = v;
    }

    if (ln31 == 0) {
        if (PART) {
            float* Sp = Spart + (size_t)c * (NL * MM) + l * MM + m0;
#pragma unroll
            for (int r = 0; r < 16; ++r) {
                const int row = (r & 3) + 8 * (r >> 2) + 4 * hf;
                Sp[row] = acc[r];
            }
        } else {
            float* Sp = Spart + l * MM + m0;
#pragma unroll
            for (int r = 0; r < 16; ++r) {
                const int row = (r & 3) + 8 * (r >> 2) + 4 * hf;
                atomicAdd(&Sp[row], acc[r]);
            }
        }
    }
}

// Final: sum chunk-partials, log, mean, constants. One workgroup of 1024.
__global__ void latent_reduce_kernel(const float* __restrict__ S,
                                     const float* __restrict__ log_sigma,
                                     float* __restrict__ out, int nparts)
{
    const int t = threadIdx.x;
    float s = 0.f;
#pragma unroll
    for (int k = 0; k < 4; ++k) {
        const int lm = k * 1024 + t;
        float sum = 0.f;
        for (int c = 0; c < nparts; ++c) sum += S[c * (NL * MM) + lm];
        s += __logf(sum);
    }
#pragma unroll
    for (int off = 32; off > 0; off >>= 1) s += __shfl_down(s, off, 64);
    __shared__ float red[16];
    if ((t & 63) == 0) red[t >> 6] = s;
    __syncthreads();
    if (t == 0) {
        float tot = 0.f;
#pragma unroll
        for (int i = 0; i < 16; ++i) tot += red[i];
        const float ls = log_sigma[0];
        out[0] = -tot / (float)(NL * MM)
               + 32.0f * (2.0f * ls - 1.0f)   // 0.5*z_dim*(2ls-1), z_dim=64
               + 9.70406052783923f;           // ln(16384)
    }
}

extern "C" void kernel_launch(void* const* d_in, const int* in_sizes, int n_in,
                              void* d_out, int out_size, void* d_ws, size_t ws_size,
                              hipStream_t stream)
{
    const float* z  = (const float*)d_in[0];
    const float* e  = (const float*)d_in[1];
    const float* ls = (const float*)d_in[2];
    float* out = (float*)d_out;
    float* S   = (float*)d_ws;

    const size_t need = (size_t)NCHUNK * NL * MM * sizeof(float); // 512 KB
    if (ws_size >= need) {
        // Partial-sum path: every (chunk,l,m) written exactly once — no memset, 2 dispatches.
        latent_dist_kernel<true><<<NL * NMG * NCHUNK, 256, 0, stream>>>(z, e, ls, S);
        latent_reduce_kernel<<<1, 1024, 0, stream>>>(S, ls, out, NCHUNK);
    } else {
        hipMemsetAsync(S, 0, NL * MM * sizeof(float), stream);
        latent_dist_kernel<false><<<NL * NMG * NCHUNK, 256, 0, stream>>>(z, e, ls, S);
        latent_reduce_kernel<<<1, 1024, 0, stream>>>(S, ls, out, 1);
    }
}

// Round 3
// 78.036 us; speedup vs baseline: 1.4497x; 1.3182x over previous
//
#include <hip/hip_runtime.h>
#include <math.h>

// Problem constants (fixed by setup_inputs)
#define NL 4          // n_latents
#define MM 1024       // codebook entries per latent
#define DD 16         // dim per latent
#define PP 16384      // points = N*H*W
#define PLANE 1024    // H*W
#define NSTRIDE 65536 // z_dim*H*W
#define CHUNK 512     // points per workgroup (half a plane)
#define NCHUNK (PP / CHUNK)   // 32
#define MGROUP 128    // codes per workgroup (4 waves x 32)
#define NMG (MM / MGROUP)     // 8
#define ZSTR 20       // LDS stride per point in f16 units (16 data + 4 pad = 40B)

#if __has_builtin(__builtin_amdgcn_exp2f)
#define EXP2(x) __builtin_amdgcn_exp2f(x)
#else
#define EXP2(x) exp2f(x)
#endif

typedef _Float16 half4v  __attribute__((ext_vector_type(4)));
typedef _Float16 half8v  __attribute__((ext_vector_type(8)));
typedef float    float16v __attribute__((ext_vector_type(16)));

// Per (l, m-strip of 32 codes, p-chunk of 512 points):
//   dd = (m2a2*e_tile)(32xK16) . z_tile(K16x32) + biasC   via v_mfma_f32_32x32x16_f16
//        where biasC[r] = a2*esq[row(r)]  (C operand, constant over the p-loop)
//   exponent(log2) = dd[r] + a2*zsq[col]
//   acc[r] += 2^exponent; shuffle-reduce over 32 cols; atomicAdd into S[l][m].
// MFMA 32x32 C/D layout (HW-verified): col=lane&31, row=(reg&3)+8*(reg>>2)+4*(lane>>5)
// A layout (verified by round-1/2 absmax=0): A[row=lane&31][k=(lane>>5)*8+j]; B same on cols.
__global__ __launch_bounds__(256, 4)
void latent_dist_kernel(const float* __restrict__ z, const float* __restrict__ e,
                        const float* __restrict__ log_sigma, float* __restrict__ S)
{
    const int t    = threadIdx.x;
    const int lane = t & 63;
    const int wave = t >> 6;
    const int ln31 = lane & 31;
    const int hf   = lane >> 5;

    const int bid = blockIdx.x;
    const int c   = bid & (NCHUNK - 1);       // p-chunk
    const int mg  = (bid >> 5) & (NMG - 1);   // m-group
    const int l   = bid >> 8;                 // latent

    const float ls    = log_sigma[0];
    const float alpha = -0.5f * __expf(-2.0f * ls);
    const float a2    = alpha * 1.44269504088896340736f; // alpha/ln2
    const float m2a2  = -2.0f * a2;

    __shared__ __attribute__((aligned(16))) _Float16 zh[CHUNK * ZSTR];
    __shared__ float azqs[CHUNK];
    __shared__ float esqs[MGROUP];

    // ---- Stage z chunk: global f32 (coalesced) -> LDS f16 point-major; exact f32 zsq.
    const int n  = c >> 1;
    const int q0 = (c & 1) * CHUNK;
    const float* zb = z + (size_t)n * NSTRIDE + (size_t)l * DD * PLANE + q0;

    float sq[2] = {0.f, 0.f};
#pragma unroll
    for (int dp = 0; dp < 8; ++dp) {
#pragma unroll
        for (int j = 0; j < 2; ++j) {
            const int pl = j * 256 + t;
            float v0 = zb[(2 * dp)     * PLANE + pl];
            float v1 = zb[(2 * dp + 1) * PLANE + pl];
            sq[j] += v0 * v0 + v1 * v1;
            union { _Float16 h[2]; unsigned u; } pk;
            pk.h[0] = (_Float16)v0; pk.h[1] = (_Float16)v1;
            *(unsigned*)(&zh[pl * ZSTR + 2 * dp]) = pk.u; // 4B-aligned packed store
        }
    }
    azqs[t]       = sq[0] * a2;
    azqs[256 + t] = sq[1] * a2;

    // ---- A fragment (codes, pre-scaled by m2a2) + exact f32 esq.
    const int m0 = mg * MGROUP + wave * 32;
    const float* eb = e + ((size_t)l * MM + m0 + ln31) * DD + hf * 8;
    float4 a0 = *(const float4*)eb;
    float4 a1 = *(const float4*)(eb + 4);
    float esq_p = a0.x*a0.x + a0.y*a0.y + a0.z*a0.z + a0.w*a0.w
                + a1.x*a1.x + a1.y*a1.y + a1.z*a1.z + a1.w*a1.w;
    esq_p += __shfl_xor(esq_p, 32, 64);           // combine the two k-halves
    esqs[wave * 32 + ln31] = esq_p;               // both halves write same value

    half8v Af;
    Af[0] = (_Float16)(a0.x * m2a2); Af[1] = (_Float16)(a0.y * m2a2);
    Af[2] = (_Float16)(a0.z * m2a2); Af[3] = (_Float16)(a0.w * m2a2);
    Af[4] = (_Float16)(a1.x * m2a2); Af[5] = (_Float16)(a1.y * m2a2);
    Af[6] = (_Float16)(a1.z * m2a2); Af[7] = (_Float16)(a1.w * m2a2);

    __syncthreads();

    // C operand = a2*esq[row(r)]: folded into the MFMA, constant over the p-loop.
    float16v biasC;
#pragma unroll
    for (int r = 0; r < 16; ++r) {
        const int row = (r & 3) + 8 * (r >> 2) + 4 * hf;
        biasC[r] = esqs[wave * 32 + row] * a2;
    }

    float16v acc;
#pragma unroll
    for (int r = 0; r < 16; ++r) acc[r] = 0.f;

    const _Float16* zrow = zh + ln31 * ZSTR + hf * 8;
#pragma unroll 2
    for (int pt = 0; pt < CHUNK / 32; ++pt) {
        const float az = azqs[pt * 32 + ln31];           // ds_read_b32 (broadcast)
        const _Float16* bp = zrow + pt * 32 * ZSTR;
        half4v b0 = *(const half4v*)bp;                  // ds_read_b64 x2, 2-way bank alias = free
        half4v b1 = *(const half4v*)(bp + 4);
        half8v Bf = __builtin_shufflevector(b0, b1, 0, 1, 2, 3, 4, 5, 6, 7);
        float16v dd = __builtin_amdgcn_mfma_f32_32x32x16_f16(Af, Bf, biasC, 0, 0, 0);
#pragma unroll
        for (int r = 0; r < 16; ++r) {
            acc[r] += EXP2(dd[r] + az);                  // 2 VALU + 1 trans per element
        }
    }

    // Reduce over the 32 cols (points) inside each half-wave.
#pragma unroll
    for (int r = 0; r < 16; ++r) {
        float v = acc[r];
        v += __shfl_xor(v, 16, 64);
        v += __shfl_xor(v, 8, 64);
        v += __shfl_xor(v, 4, 64);
        v += __shfl_xor(v, 2, 64);
        v += __shfl_xor(v, 1, 64);
        acc[r] = v;
    }

    if (ln31 == 0) {
        float* Sp = S + l * MM + m0;
#pragma unroll
        for (int r = 0; r < 16; ++r) {
            const int row = (r & 3) + 8 * (r >> 2) + 4 * hf;
            atomicAdd(&Sp[row], acc[r]);   // 32 adds per address total — negligible contention
        }
    }
}

// Final: log, mean, constants. One workgroup of 1024 reading 16 KB.
__global__ void latent_reduce_kernel(const float* __restrict__ S,
                                     const float* __restrict__ log_sigma,
                                     float* __restrict__ out)
{
    const int t = threadIdx.x;
    float s = 0.f;
#pragma unroll
    for (int k = 0; k < 4; ++k) s += __logf(S[k * 1024 + t]);
#pragma unroll
    for (int off = 32; off > 0; off >>= 1) s += __shfl_down(s, off, 64);
    __shared__ float red[16];
    if ((t & 63) == 0) red[t >> 6] = s;
    __syncthreads();
    if (t == 0) {
        float tot = 0.f;
#pragma unroll
        for (int i = 0; i < 16; ++i) tot += red[i];
        const float ls = log_sigma[0];
        out[0] = -tot / (float)(NL * MM)
               + 32.0f * (2.0f * ls - 1.0f)   // 0.5*z_dim*(2ls-1), z_dim=64
               + 9.70406052783923f;           // ln(16384)
    }
}

extern "C" void kernel_launch(void* const* d_in, const int* in_sizes, int n_in,
                              void* d_out, int out_size, void* d_ws, size_t ws_size,
                              hipStream_t stream)
{
    const float* z  = (const float*)d_in[0];
    const float* e  = (const float*)d_in[1];
    const float* ls = (const float*)d_in[2];
    float* out = (float*)d_out;
    float* S   = (float*)d_ws;

    // ws is re-poisoned to 0xAA before every launch; zero the 16 KB accumulator.
    hipMemsetAsync(S, 0, NL * MM * sizeof(float), stream);
    latent_dist_kernel<<<NL * NMG * NCHUNK, 256, 0, stream>>>(z, e, ls, S);
    latent_reduce_kernel<<<1, 1024, 0, stream>>>(S, ls, out);
}